// Round 9
// baseline (17687.877 us; speedup 1.0000x reference)
//
#include <hip/hip_runtime.h>

typedef float v4f __attribute__((ext_vector_type(4)));
typedef _Float16 h8 __attribute__((ext_vector_type(8)));

#define TT 512
#define BB 4096
#define BT 16
#define NTH 256
#define ARS 328              // A row stride in fp16 (80*4 cols + pad)
#define NHB 36               // half-steps per time-step (18 k-steps x {hi,lo})
#define HBB 20480            // bytes per half-step block (20 tiles x 64 lanes x 16 B)

// ---- dynamic-LDS byte offsets ----
#define WRING_OFF 0          // 4 waves x 4 slots x 5120 B  (per-wave B ring)
#define GATES_OFF 81920      // float[320*20]
#define AHI_OFF  107520      // _Float16[16*ARS]
#define ALO_OFF  118016      // _Float16[16*ARS]
#define H2_OFF   128512      // float[80*16]
#define BIAS_OFF 133632      // float[4*320]
#define WIH1_OFF 138752      // float[320]
#define WLIN_OFF 140032      // float[80]
#define XB_OFF   140352      // float[16]
#define LDS_BYTES 140416

// ---------------- prep: pack weights as fp16 hi/lo B-fragment stream ----------------
// stream element order: [halfstep hb][tile T 0..19][lane L 0..63][j 0..7] fp16
// k-step map: ks 0..17 -> layer l (3,5,5,5 steps), hb = 2*ks (+1 for lo)
// B value at (n = 16T + (L&15), k = 32s + (L>>4)*8 + j), window-relative k:
//   l==0: k<80 -> whh1[n][k], else 0 (zero-padded tail rows)
//   l>=1: k<80 -> wih_l[n][k] (x-source = h_{l-1}), else whh_l[n][k-80]
__global__ void prep_pack(const float* __restrict__ whh1,
                          const float* __restrict__ wih2, const float* __restrict__ whh2,
                          const float* __restrict__ wih3, const float* __restrict__ whh3,
                          const float* __restrict__ wih4, const float* __restrict__ whh4,
                          _Float16* __restrict__ stream)
{
  int e = blockIdx.x * blockDim.x + threadIdx.x;
  if (e >= NHB * (HBB / 2)) return;
  int hb = e / (HBB / 2);
  int r  = e - hb * (HBB / 2);
  int T  = r >> 9;
  int r2 = r & 511;
  int L  = r2 >> 3;
  int j  = r2 & 7;
  int ks = hb >> 1;
  int is_lo = hb & 1;
  int l = (ks < 3) ? 0 : (ks < 8) ? 1 : (ks < 13) ? 2 : 3;
  int s = ks - ((l == 0) ? 0 : (l == 1) ? 3 : (l == 2) ? 8 : 13);
  int n = 16 * T + (L & 15);
  int k = 32 * s + ((L >> 4) << 3) + j;
  float w;
  if (l == 0) {
    w = (k < 80) ? whh1[n * 80 + k] : 0.f;
  } else {
    const float* wih = (l == 1) ? wih2 : (l == 2) ? wih3 : wih4;
    const float* whh = (l == 1) ? whh2 : (l == 2) ? whh3 : whh4;
    w = (k < 80) ? wih[n * 80 + k] : whh[n * 80 + (k - 80)];
  }
  _Float16 hi = (_Float16)w;
  _Float16 v = is_lo ? (_Float16)((w - (float)hi) * 4096.f) : hi;
  stream[e] = v;
}

// ---------------- main persistent LSTM kernel ----------------
__device__ __forceinline__ float sigm(float x) {
  return __builtin_amdgcn_rcpf(1.f + __expf(-x));
}
__device__ __forceinline__ float tanh_fast(float x) {
  return 1.f - 2.f * __builtin_amdgcn_rcpf(1.f + __expf(2.f * x));
}
// barrier WITHOUT vmcnt drain: keeps staged global->LDS loads in flight
__device__ __forceinline__ void bar() {
  asm volatile("s_waitcnt lgkmcnt(0)" ::: "memory");
  __builtin_amdgcn_s_barrier();
  asm volatile("" ::: "memory");
}

typedef __attribute__((address_space(1))) void gvoid_t;
typedef __attribute__((address_space(3))) void svoid_t;

// stage half-step hq's 5-tile slice for wave wv into its ring slot (hq&3).
// 5 x global_load_lds width-16: dst wave-uniform base + lane*16 (linear), src per-lane.
__device__ __forceinline__ void stage(const char* stream, char* wring,
                                      int wv, int lane, int hq) {
  const int hb = hq % NHB;       // compile-time after unroll
  const int slot = hq & 3;       // consistent with %NHB since NHB%4==0
  const char* src = stream + hb * HBB + wv * 5120 + lane * 16;
  char* dst = wring + wv * 20480 + slot * 5120;
#pragma unroll
  for (int i = 0; i < 5; ++i)
    __builtin_amdgcn_global_load_lds((gvoid_t*)(src + i * 1024),
                                     (svoid_t*)(dst + i * 1024), 16, 0, 0);
}

__global__ void __launch_bounds__(NTH, 1)
lstm_main(const float* __restrict__ input,
          const _Float16* __restrict__ stream,
          const float* __restrict__ bih1, const float* __restrict__ bhh1,
          const float* __restrict__ bih2, const float* __restrict__ bhh2,
          const float* __restrict__ bih3, const float* __restrict__ bhh3,
          const float* __restrict__ bih4, const float* __restrict__ bhh4,
          const float* __restrict__ wih1, const float* __restrict__ wlin,
          const float* __restrict__ blin, float* __restrict__ out)
{
  extern __shared__ __align__(16) char smraw[];
  char*      wring   = smraw + WRING_OFF;
  float*     s_gates = (float*)(smraw + GATES_OFF);
  _Float16*  s_Ahi   = (_Float16*)(smraw + AHI_OFF);
  _Float16*  s_Alo   = (_Float16*)(smraw + ALO_OFF);
  float*     s_h2    = (float*)(smraw + H2_OFF);
  float*     s_bias  = (float*)(smraw + BIAS_OFF);
  float*     s_wih1  = (float*)(smraw + WIH1_OFF);
  float*     s_wlin  = (float*)(smraw + WLIN_OFF);
  float*     s_xb    = (float*)(smraw + XB_OFF);

  const int tid  = threadIdx.x;
  const int lane = tid & 63;
  const int wv   = tid >> 6;
  const int b0   = blockIdx.x * BT;
  const int m15  = lane & 15;
  const int quad = lane >> 4;
  const int mb   = quad * 4;       // C rows (batches) mb..mb+3
  const int jb   = tid & 15;       // activation: batch
  const int j0   = tid >> 4;       // activation: hidden base

  // ---- init ----
  for (int i = tid; i < 320; i += NTH) {
    s_bias[i]       = bih1[i] + bhh1[i];
    s_bias[320 + i] = bih2[i] + bhh2[i];
    s_bias[640 + i] = bih3[i] + bhh3[i];
    s_bias[960 + i] = bih4[i] + bhh4[i];
    s_wih1[i] = wih1[i];
  }
  for (int i = tid; i < 80; i += NTH) s_wlin[i] = wlin[i];
  for (int i = tid; i < 16 * ARS / 2; i += NTH) {
    ((unsigned*)s_Ahi)[i] = 0u;
    ((unsigned*)s_Alo)[i] = 0u;
  }
  if (tid < 16) s_xb[tid] = input[(b0 + tid) * TT];
  const float blinv = blin[0];

  const char* st8 = (const char*)stream;
  const char* wbase = wring + wv * 20480;
  const int lane16 = lane * 16;

  // prologue: stage slices 0..3 (per-wave ring; 20 loads outstanding)
  stage(st8, wring, wv, lane, 0);
  stage(st8, wring, wv, lane, 1);
  stage(st8, wring, wv, lane, 2);
  stage(st8, wring, wv, lane, 3);

  float creg[4][5];
#pragma unroll
  for (int l = 0; l < 4; ++l)
#pragma unroll
    for (int i = 0; i < 5; ++i) creg[l][i] = 0.f;

  float xreg = 0.f;
  bar();   // for s_bias/s_Ahi/s_xb init visibility (no vmcnt drain)

  for (int t = 0; t < TT; ++t) {
#pragma unroll
    for (int l = 0; l < 4; ++l) {
      const int NSL = (l == 0) ? 3 : 5;
      const int KBL = (l == 0) ? 0 : (l == 1) ? 3 : (l == 2) ? 8 : 13;
      const int CBL = (l == 0) ? 0 : 80 * (l - 1);   // A window start col

      // ---- accumulator init: bias (+ x*w_ih1 for layer 1) ----
      v4f acch[5], accl[5];
#pragma unroll
      for (int tl = 0; tl < 5; ++tl) {
        const int n = 16 * (5 * wv + tl) + m15;
        const float b = s_bias[l * 320 + n];
        v4f a;
        if (l == 0) {
          const float wi = s_wih1[n];
#pragma unroll
          for (int r = 0; r < 4; ++r) a[r] = b + s_xb[mb + r] * wi;
        } else {
#pragma unroll
          for (int r = 0; r < 4; ++r) a[r] = b;
        }
        acch[tl] = a;
        accl[tl] = (v4f){0.f, 0.f, 0.f, 0.f};
      }

      // ---- MFMA K loop: race-free ring schedule per iteration:
      //   vmcnt(10)  -> slices q,q+1 resident (staged 2 iters ago)
      //   ds_read bhi,blo,A-next ; lgkmcnt(0)+sched_barrier  (reads COMPLETE)
      //   stage(q+4),stage(q+5)  (overwrite exactly the two drained slots)
      //   15 MFMAs
      const int ab0 = m15 * ARS + CBL + quad * 8;
      h8 ahi = *(const h8*)&s_Ahi[ab0];
      h8 alo = *(const h8*)&s_Alo[ab0];
#pragma unroll
      for (int s = 0; s < NSL; ++s) {
        const int q = 2 * (KBL + s);         // hi half-step index (0..34, compile-time)
        asm volatile("s_waitcnt vmcnt(10)" ::: "memory");
        h8 bhi[5], blo[5];
#pragma unroll
        for (int tl = 0; tl < 5; ++tl)
          bhi[tl] = *(const h8*)(wbase + (q & 3) * 5120 + tl * 1024 + lane16);
#pragma unroll
        for (int tl = 0; tl < 5; ++tl)
          blo[tl] = *(const h8*)(wbase + ((q + 1) & 3) * 5120 + tl * 1024 + lane16);
        h8 anh, anl;
        if (s + 1 < NSL) {
          anh = *(const h8*)&s_Ahi[ab0 + 32 * (s + 1)];
          anl = *(const h8*)&s_Alo[ab0 + 32 * (s + 1)];
        }
        asm volatile("s_waitcnt lgkmcnt(0)" ::: "memory");
        __builtin_amdgcn_sched_barrier(0);
        stage(st8, wring, wv, lane, q + 4);
        stage(st8, wring, wv, lane, q + 5);
#pragma unroll
        for (int tl = 0; tl < 5; ++tl)
          acch[tl] = __builtin_amdgcn_mfma_f32_16x16x32_f16(ahi, bhi[tl], acch[tl], 0, 0, 0);
#pragma unroll
        for (int tl = 0; tl < 5; ++tl)
          accl[tl] = __builtin_amdgcn_mfma_f32_16x16x32_f16(alo, bhi[tl], accl[tl], 0, 0, 0);
#pragma unroll
        for (int tl = 0; tl < 5; ++tl)
          accl[tl] = __builtin_amdgcn_mfma_f32_16x16x32_f16(ahi, blo[tl], accl[tl], 0, 0, 0);
        if (s + 1 < NSL) { ahi = anh; alo = anl; }
      }

      // ---- C write: gates[n][m] ----
#pragma unroll
      for (int tl = 0; tl < 5; ++tl) {
        const int n = 16 * (5 * wv + tl) + m15;
        v4f o = acch[tl] + accl[tl] * 0.000244140625f;   // + lo-acc * 2^-12
        *(v4f*)&s_gates[n * 20 + mb] = o;
      }
      bar();

      // ---- activation: c in regs, h -> fp16 hi/lo A-fragments ----
#pragma unroll
      for (int i = 0; i < 5; ++i) {
        const int j = j0 + 16 * i;
        const float gi = s_gates[j * 20 + jb];
        const float gf = s_gates[(80 + j) * 20 + jb];
        const float gg = s_gates[(160 + j) * 20 + jb];
        const float go = s_gates[(240 + j) * 20 + jb];
        const float cn = sigm(gf) * creg[l][i] + sigm(gi) * tanh_fast(gg);
        creg[l][i] = cn;
        const float h = sigm(go) * tanh_fast(cn);
        const _Float16 hh = (_Float16)h;
        s_Ahi[jb * ARS + 80 * l + j] = hh;
        s_Alo[jb * ARS + 80 * l + j] = (_Float16)((h - (float)hh) * 4096.f);
        if (l == 1) s_h2[j * 16 + jb] = h;
      }
      if (l == 0 && tid < 16)
        xreg = input[(b0 + tid) * TT + ((t + 1 < TT) ? (t + 1) : t)];
      if (l == 3 && tid < 16) s_xb[tid] = xreg;
      bar();

      // ---- output = h2 @ w_lin + b_lin ----
      if (l == 1 && tid < 64) {
        const int ob = tid >> 2, kp = tid & 3;
        float p = 0.f;
#pragma unroll
        for (int k = 0; k < 20; ++k)
          p = fmaf(s_h2[(kp * 20 + k) * 16 + ob], s_wlin[kp * 20 + k], p);
        p += __shfl_xor(p, 1);
        p += __shfl_xor(p, 2);
        if (kp == 0) out[(b0 + ob) * TT + t] = p + blinv;
      }
    }
  }
}

// ---------------- host launcher ----------------
extern "C" void kernel_launch(void* const* d_in, const int* in_sizes, int n_in,
                              void* d_out, int out_size, void* d_ws, size_t ws_size,
                              hipStream_t stream) {
  const float* input = (const float*)d_in[0];
  const float* wih1 = (const float*)d_in[1];
  const float* whh1 = (const float*)d_in[2];
  const float* bih1 = (const float*)d_in[3];
  const float* bhh1 = (const float*)d_in[4];
  const float* wih2 = (const float*)d_in[5];
  const float* whh2 = (const float*)d_in[6];
  const float* bih2 = (const float*)d_in[7];
  const float* bhh2 = (const float*)d_in[8];
  const float* wih3 = (const float*)d_in[9];
  const float* whh3 = (const float*)d_in[10];
  const float* bih3 = (const float*)d_in[11];
  const float* bhh3 = (const float*)d_in[12];
  const float* wih4 = (const float*)d_in[13];
  const float* whh4 = (const float*)d_in[14];
  const float* bih4 = (const float*)d_in[15];
  const float* bhh4 = (const float*)d_in[16];
  const float* wlin = (const float*)d_in[17];
  const float* blin = (const float*)d_in[18];
  _Float16* ws = (_Float16*)d_ws;
  float* out = (float*)d_out;

  hipLaunchKernelGGL(prep_pack, dim3((NHB * (HBB / 2) + 255) / 256), dim3(256), 0,
                     stream, whh1, wih2, whh2, wih3, whh3, wih4, whh4, ws);

  hipFuncSetAttribute(reinterpret_cast<const void*>(lstm_main),
                      hipFuncAttributeMaxDynamicSharedMemorySize, LDS_BYTES);
  hipLaunchKernelGGL(lstm_main, dim3(BB / BT), dim3(NTH), LDS_BYTES, stream,
                     input, ws,
                     bih1, bhh1, bih2, bhh2, bih3, bhh3, bih4, bhh4,
                     wih1, wlin, blin, out);
}

// Round 11
// 16408.446 us; speedup vs baseline: 1.0780x; 1.0780x over previous
//
#include <hip/hip_runtime.h>

typedef float v4f __attribute__((ext_vector_type(4)));
typedef _Float16 h8 __attribute__((ext_vector_type(8)));

#define TT 512
#define BB 4096
#define BT 16
#define NTH 640              // 10 waves: 2 N-tiles per wave -> >=2 waves/SIMD
#define ARS 328              // A row stride in fp16 (80*4 cols + pad)
#define NHB 36               // half-steps per time-step (18 k-steps x {hi,lo})
#define HBB 20480            // bytes per half-step block (20 tiles x 64 lanes x 16 B)

// ---- dynamic-LDS byte offsets ----
#define WRING_OFF 0          // 10 waves x 4 slots x 2048 B  (per-wave B ring)
#define GATES_OFF 81920      // float[320*20]
#define AHI_OFF  107520      // _Float16[16*ARS]
#define ALO_OFF  118016      // _Float16[16*ARS]
#define H2_OFF   128512      // float[80*16]
#define BIAS_OFF 133632      // float[4*320]
#define WIH1_OFF 138752      // float[320]
#define WLIN_OFF 140032      // float[80]
#define XB_OFF   140352      // float[16]
#define LDS_BYTES 140416

// ---------------- prep: pack weights as fp16 hi/lo B-fragment stream ----------------
// stream element order: [halfstep hb][tile T 0..19][lane L 0..63][j 0..7] fp16
// k-step map: ks 0..17 -> layer l (3,5,5,5 steps), hb = 2*ks (+1 for lo)
// B value at (n = 16T + (L&15), k = 32s + (L>>4)*8 + j), window-relative k:
//   l==0: k<80 -> whh1[n][k], else 0 (zero-padded tail rows)
//   l>=1: k<80 -> wih_l[n][k] (x-source = h_{l-1}), else whh_l[n][k-80]
__global__ void prep_pack(const float* __restrict__ whh1,
                          const float* __restrict__ wih2, const float* __restrict__ whh2,
                          const float* __restrict__ wih3, const float* __restrict__ whh3,
                          const float* __restrict__ wih4, const float* __restrict__ whh4,
                          _Float16* __restrict__ stream)
{
  int e = blockIdx.x * blockDim.x + threadIdx.x;
  if (e >= NHB * (HBB / 2)) return;
  int hb = e / (HBB / 2);
  int r  = e - hb * (HBB / 2);
  int T  = r >> 9;
  int r2 = r & 511;
  int L  = r2 >> 3;
  int j  = r2 & 7;
  int ks = hb >> 1;
  int is_lo = hb & 1;
  int l = (ks < 3) ? 0 : (ks < 8) ? 1 : (ks < 13) ? 2 : 3;
  int s = ks - ((l == 0) ? 0 : (l == 1) ? 3 : (l == 2) ? 8 : 13);
  int n = 16 * T + (L & 15);
  int k = 32 * s + ((L >> 4) << 3) + j;
  float w;
  if (l == 0) {
    w = (k < 80) ? whh1[n * 80 + k] : 0.f;
  } else {
    const float* wih = (l == 1) ? wih2 : (l == 2) ? wih3 : wih4;
    const float* whh = (l == 1) ? whh2 : (l == 2) ? whh3 : whh4;
    w = (k < 80) ? wih[n * 80 + k] : whh[n * 80 + (k - 80)];
  }
  _Float16 hi = (_Float16)w;
  _Float16 v = is_lo ? (_Float16)((w - (float)hi) * 4096.f) : hi;
  stream[e] = v;
}

// ---------------- main persistent LSTM kernel ----------------
__device__ __forceinline__ float sigm(float x) {
  return __builtin_amdgcn_rcpf(1.f + __expf(-x));
}
__device__ __forceinline__ float tanh_fast(float x) {
  return 1.f - 2.f * __builtin_amdgcn_rcpf(1.f + __expf(2.f * x));
}
// barrier WITHOUT vmcnt drain: keeps staged global->LDS loads in flight
__device__ __forceinline__ void bar() {
  asm volatile("s_waitcnt lgkmcnt(0)" ::: "memory");
  __builtin_amdgcn_s_barrier();
  asm volatile("" ::: "memory");
}

typedef __attribute__((address_space(1))) void gvoid_t;
typedef __attribute__((address_space(3))) void svoid_t;

// stage half-step hq's 2-tile slice for wave wv into its ring slot (hq&3).
// 2 x global_load_lds width-16: dst wave-uniform base + lane*16 (linear), src per-lane.
__device__ __forceinline__ void stage(const char* stream, char* wring,
                                      int wv, int lane, int hq) {
  const int hb = hq % NHB;       // compile-time after unroll
  const int slot = hq & 3;       // consistent with %NHB since NHB%4==0
  const char* src = stream + hb * HBB + wv * 2048 + lane * 16;
  char* dst = wring + wv * 8192 + slot * 2048;
  __builtin_amdgcn_global_load_lds((gvoid_t*)(src),
                                   (svoid_t*)(dst), 16, 0, 0);
  __builtin_amdgcn_global_load_lds((gvoid_t*)(src + 1024),
                                   (svoid_t*)(dst + 1024), 16, 0, 0);
}

__global__ void __launch_bounds__(NTH, 1)
lstm_main(const float* __restrict__ input,
          const _Float16* __restrict__ stream,
          const float* __restrict__ bih1, const float* __restrict__ bhh1,
          const float* __restrict__ bih2, const float* __restrict__ bhh2,
          const float* __restrict__ bih3, const float* __restrict__ bhh3,
          const float* __restrict__ bih4, const float* __restrict__ bhh4,
          const float* __restrict__ wih1, const float* __restrict__ wlin,
          const float* __restrict__ blin, float* __restrict__ out)
{
  extern __shared__ __align__(16) char smraw[];
  char*      wring   = smraw + WRING_OFF;
  float*     s_gates = (float*)(smraw + GATES_OFF);
  _Float16*  s_Ahi   = (_Float16*)(smraw + AHI_OFF);
  _Float16*  s_Alo   = (_Float16*)(smraw + ALO_OFF);
  float*     s_h2    = (float*)(smraw + H2_OFF);
  float*     s_bias  = (float*)(smraw + BIAS_OFF);
  float*     s_wih1  = (float*)(smraw + WIH1_OFF);
  float*     s_wlin  = (float*)(smraw + WLIN_OFF);
  float*     s_xb    = (float*)(smraw + XB_OFF);

  const int tid  = threadIdx.x;
  const int lane = tid & 63;
  const int wv   = tid >> 6;       // wave 0..9, owns N-tiles {2wv, 2wv+1}
  const int b0   = blockIdx.x * BT;
  const int m15  = lane & 15;
  const int quad = lane >> 4;
  const int mb   = quad * 4;       // C rows (batches) mb..mb+3
  const int jb   = tid & 15;       // activation: batch
  const int j0   = tid >> 4;       // activation: hidden base 0..39

  // ---- init ----
  for (int i = tid; i < 320; i += NTH) {
    s_bias[i]       = bih1[i] + bhh1[i];
    s_bias[320 + i] = bih2[i] + bhh2[i];
    s_bias[640 + i] = bih3[i] + bhh3[i];
    s_bias[960 + i] = bih4[i] + bhh4[i];
    s_wih1[i] = wih1[i];
  }
  for (int i = tid; i < 80; i += NTH) s_wlin[i] = wlin[i];
  for (int i = tid; i < 16 * ARS / 2; i += NTH) {
    ((unsigned*)s_Ahi)[i] = 0u;
    ((unsigned*)s_Alo)[i] = 0u;
  }
  if (tid < 16) s_xb[tid] = input[(b0 + tid) * TT];
  const float blinv = blin[0];

  const char* st8 = (const char*)stream;
  const char* wbase = wring + wv * 8192;
  const int lane16 = lane * 16;

  // prologue: stage slices 0..3 (per-wave ring; 8 loads outstanding)
  stage(st8, wring, wv, lane, 0);
  stage(st8, wring, wv, lane, 1);
  stage(st8, wring, wv, lane, 2);
  stage(st8, wring, wv, lane, 3);

  float creg[4][2];
#pragma unroll
  for (int l = 0; l < 4; ++l)
#pragma unroll
    for (int i = 0; i < 2; ++i) creg[l][i] = 0.f;

  float xreg = 0.f;
  bar();   // for s_bias/s_Ahi/s_xb init visibility (no vmcnt drain)

  for (int t = 0; t < TT; ++t) {
#pragma unroll
    for (int l = 0; l < 4; ++l) {
      const int NSL = (l == 0) ? 3 : 5;
      const int KBL = (l == 0) ? 0 : (l == 1) ? 3 : (l == 2) ? 8 : 13;
      const int CBL = (l == 0) ? 0 : 80 * (l - 1);   // A window start col

      // ---- accumulator init: bias (+ x*w_ih1 for layer 1) ----
      v4f acch[2], accl[2];
#pragma unroll
      for (int tl = 0; tl < 2; ++tl) {
        const int n = 16 * (2 * wv + tl) + m15;
        const float b = s_bias[l * 320 + n];
        v4f a;
        if (l == 0) {
          const float wi = s_wih1[n];
#pragma unroll
          for (int r = 0; r < 4; ++r) a[r] = b + s_xb[mb + r] * wi;
        } else {
#pragma unroll
          for (int r = 0; r < 4; ++r) a[r] = b;
        }
        acch[tl] = a;
        accl[tl] = (v4f){0.f, 0.f, 0.f, 0.f};
      }

      // ---- MFMA K loop: race-free ring schedule per iteration:
      //   vmcnt(4)   -> slices q,q+1 resident (staged 2 iters ago)
      //   ds_read bhi,blo,A-next ; lgkmcnt(0)+sched_barrier  (reads COMPLETE)
      //   stage(q+4),stage(q+5)  (overwrite exactly the two drained slots)
      //   6 MFMAs
      const int ab0 = m15 * ARS + CBL + quad * 8;
      h8 ahi = *(const h8*)&s_Ahi[ab0];
      h8 alo = *(const h8*)&s_Alo[ab0];
#pragma unroll
      for (int s = 0; s < NSL; ++s) {
        const int q = 2 * (KBL + s);         // hi half-step index (0..34, compile-time)
        asm volatile("s_waitcnt vmcnt(4)" ::: "memory");
        h8 bhi[2], blo[2];
#pragma unroll
        for (int tl = 0; tl < 2; ++tl)
          bhi[tl] = *(const h8*)(wbase + (q & 3) * 2048 + tl * 1024 + lane16);
#pragma unroll
        for (int tl = 0; tl < 2; ++tl)
          blo[tl] = *(const h8*)(wbase + ((q + 1) & 3) * 2048 + tl * 1024 + lane16);
        h8 anh, anl;
        if (s + 1 < NSL) {
          anh = *(const h8*)&s_Ahi[ab0 + 32 * (s + 1)];
          anl = *(const h8*)&s_Alo[ab0 + 32 * (s + 1)];
        }
        asm volatile("s_waitcnt lgkmcnt(0)" ::: "memory");
        __builtin_amdgcn_sched_barrier(0);
        stage(st8, wring, wv, lane, q + 4);
        stage(st8, wring, wv, lane, q + 5);
#pragma unroll
        for (int tl = 0; tl < 2; ++tl)
          acch[tl] = __builtin_amdgcn_mfma_f32_16x16x32_f16(ahi, bhi[tl], acch[tl], 0, 0, 0);
#pragma unroll
        for (int tl = 0; tl < 2; ++tl)
          accl[tl] = __builtin_amdgcn_mfma_f32_16x16x32_f16(alo, bhi[tl], accl[tl], 0, 0, 0);
#pragma unroll
        for (int tl = 0; tl < 2; ++tl)
          accl[tl] = __builtin_amdgcn_mfma_f32_16x16x32_f16(ahi, blo[tl], accl[tl], 0, 0, 0);
        if (s + 1 < NSL) { ahi = anh; alo = anl; }
      }

      // ---- C write: gates[n][m] ----
#pragma unroll
      for (int tl = 0; tl < 2; ++tl) {
        const int n = 16 * (2 * wv + tl) + m15;
        v4f o = acch[tl] + accl[tl] * 0.000244140625f;   // + lo-acc * 2^-12
        *(v4f*)&s_gates[n * 20 + mb] = o;
      }
      bar();

      // ---- activation: c in regs, h -> fp16 hi/lo A-fragments (2 j's/thread) ----
#pragma unroll
      for (int i = 0; i < 2; ++i) {
        const int j = j0 + 40 * i;
        const float gi = s_gates[j * 20 + jb];
        const float gf = s_gates[(80 + j) * 20 + jb];
        const float gg = s_gates[(160 + j) * 20 + jb];
        const float go = s_gates[(240 + j) * 20 + jb];
        const float cn = sigm(gf) * creg[l][i] + sigm(gi) * tanh_fast(gg);
        creg[l][i] = cn;
        const float h = sigm(go) * tanh_fast(cn);
        const _Float16 hh = (_Float16)h;
        s_Ahi[jb * ARS + 80 * l + j] = hh;
        s_Alo[jb * ARS + 80 * l + j] = (_Float16)((h - (float)hh) * 4096.f);
        if (l == 1) s_h2[j * 16 + jb] = h;
      }
      if (l == 0 && tid < 16)
        xreg = input[(b0 + tid) * TT + ((t + 1 < TT) ? (t + 1) : t)];
      if (l == 3 && tid < 16) s_xb[tid] = xreg;
      bar();

      // ---- output = h2 @ w_lin + b_lin ----
      if (l == 1 && tid < 64) {
        const int ob = tid >> 2, kp = tid & 3;
        float p = 0.f;
#pragma unroll
        for (int k = 0; k < 20; ++k)
          p = fmaf(s_h2[(kp * 20 + k) * 16 + ob], s_wlin[kp * 20 + k], p);
        p += __shfl_xor(p, 1);
        p += __shfl_xor(p, 2);
        if (kp == 0) out[(b0 + ob) * TT + t] = p + blinv;
      }
    }
  }
}

// ---------------- host launcher ----------------
extern "C" void kernel_launch(void* const* d_in, const int* in_sizes, int n_in,
                              void* d_out, int out_size, void* d_ws, size_t ws_size,
                              hipStream_t stream) {
  const float* input = (const float*)d_in[0];
  const float* wih1 = (const float*)d_in[1];
  const float* whh1 = (const float*)d_in[2];
  const float* bih1 = (const float*)d_in[3];
  const float* bhh1 = (const float*)d_in[4];
  const float* wih2 = (const float*)d_in[5];
  const float* whh2 = (const float*)d_in[6];
  const float* bih2 = (const float*)d_in[7];
  const float* bhh2 = (const float*)d_in[8];
  const float* wih3 = (const float*)d_in[9];
  const float* whh3 = (const float*)d_in[10];
  const float* bih3 = (const float*)d_in[11];
  const float* bhh3 = (const float*)d_in[12];
  const float* wih4 = (const float*)d_in[13];
  const float* whh4 = (const float*)d_in[14];
  const float* bih4 = (const float*)d_in[15];
  const float* bhh4 = (const float*)d_in[16];
  const float* wlin = (const float*)d_in[17];
  const float* blin = (const float*)d_in[18];
  _Float16* ws = (_Float16*)d_ws;
  float* out = (float*)d_out;

  hipLaunchKernelGGL(prep_pack, dim3((NHB * (HBB / 2) + 255) / 256), dim3(256), 0,
                     stream, whh1, wih2, whh2, wih3, whh3, wih4, whh4, ws);

  hipFuncSetAttribute(reinterpret_cast<const void*>(lstm_main),
                      hipFuncAttributeMaxDynamicSharedMemorySize, LDS_BYTES);
  hipLaunchKernelGGL(lstm_main, dim3(BB / BT), dim3(NTH), LDS_BYTES, stream,
                     input, ws,
                     bih1, bhh1, bih2, bhh2, bih3, bhh3, bih4, bhh4,
                     wih1, wlin, blin, out);
}